// Round 1
// baseline (1335.244 us; speedup 1.0000x reference)
//
#include <hip/hip_runtime.h>
#include <hip/hip_bf16.h>
#include <math.h>

#define NNODES 20000
#define NEDGES 320000
#define HDIM   128
#define INDIM  256
#define INV_SCALE (1.0f/30.0f)
#define LN_EPS 1e-5f

__device__ __forceinline__ float gelu_f(float x) {
    // exact (erf) gelu, matches torch F.gelu default / jax approximate=False
    return 0.5f * x * (1.0f + erff(x * 0.7071067811865476f));
}

// ---------------------------------------------------------------------------
// Edge MLP: h_msg = W3(gelu(W2(gelu(W1(h_E))))) fused, then atomic scatter-add
// into dh[src]. 32 edges per block, 256 threads, 4x4 register microtile per
// thread (hb = output-channel quad, eb = edge quad).
// ---------------------------------------------------------------------------
template<int K>
__device__ __forceinline__ void tile_gemm_acc(const float* __restrict__ Wm,
                                              const float* __restrict__ src_lds,
                                              int e4, int h4, float acc[4][4]) {
    for (int k = 0; k < K; k += 4) {
        const float4 w0 = *(const float4*)(Wm + (k + 0) * HDIM + h4);
        const float4 w1 = *(const float4*)(Wm + (k + 1) * HDIM + h4);
        const float4 w2 = *(const float4*)(Wm + (k + 2) * HDIM + h4);
        const float4 w3 = *(const float4*)(Wm + (k + 3) * HDIM + h4);
        #pragma unroll
        for (int i = 0; i < 4; ++i) {
            const float4 xv = *(const float4*)(src_lds + (e4 + i) * K + k);
            acc[i][0] += xv.x * w0.x + xv.y * w1.x + xv.z * w2.x + xv.w * w3.x;
            acc[i][1] += xv.x * w0.y + xv.y * w1.y + xv.z * w2.y + xv.w * w3.y;
            acc[i][2] += xv.x * w0.z + xv.y * w1.z + xv.z * w2.z + xv.w * w3.z;
            acc[i][3] += xv.x * w0.w + xv.y * w1.w + xv.z * w2.w + xv.w * w3.w;
        }
    }
}

__launch_bounds__(256)
__global__ void edge_mlp_kernel(const float* __restrict__ hE,
                                const int* __restrict__ edge_idx,
                                const float* __restrict__ W1, const float* __restrict__ b1,
                                const float* __restrict__ W2, const float* __restrict__ b2,
                                const float* __restrict__ W3, const float* __restrict__ b3,
                                float* __restrict__ dh) {
    __shared__ float Xs[32 * INDIM];   // 32 KB; reused as Y2 (stride 128) later
    __shared__ float Y1s[32 * HDIM];   // 16 KB

    const int tid = threadIdx.x;
    const int e0 = blockIdx.x * 32;

    // stage 32 full h_E rows (contiguous 32*256 floats) into LDS
    {
        const float4* src = (const float4*)(hE + (size_t)e0 * INDIM);
        for (int i = tid; i < 32 * INDIM / 4; i += 256)
            ((float4*)Xs)[i] = src[i];
    }
    __syncthreads();

    const int hb = tid & 31;   // output-channel quad index
    const int h4 = hb * 4;
    const int eb = tid >> 5;   // edge quad index (0..7)
    const int e4 = eb * 4;

    float acc[4][4];

    // ---- layer 1: K=256, gelu ----
    {
        const float4 bv = *(const float4*)(b1 + h4);
        #pragma unroll
        for (int i = 0; i < 4; ++i) { acc[i][0] = bv.x; acc[i][1] = bv.y; acc[i][2] = bv.z; acc[i][3] = bv.w; }
        tile_gemm_acc<INDIM>(W1, Xs, e4, h4, acc);
        #pragma unroll
        for (int i = 0; i < 4; ++i) {
            float4 v;
            v.x = gelu_f(acc[i][0]); v.y = gelu_f(acc[i][1]);
            v.z = gelu_f(acc[i][2]); v.w = gelu_f(acc[i][3]);
            *(float4*)(Y1s + (e4 + i) * HDIM + h4) = v;
        }
    }
    __syncthreads();

    // ---- layer 2: K=128, gelu, write into Xs region (as Y2, stride 128) ----
    {
        const float4 bv = *(const float4*)(b2 + h4);
        #pragma unroll
        for (int i = 0; i < 4; ++i) { acc[i][0] = bv.x; acc[i][1] = bv.y; acc[i][2] = bv.z; acc[i][3] = bv.w; }
        tile_gemm_acc<HDIM>(W2, Y1s, e4, h4, acc);
        #pragma unroll
        for (int i = 0; i < 4; ++i) {
            float4 v;
            v.x = gelu_f(acc[i][0]); v.y = gelu_f(acc[i][1]);
            v.z = gelu_f(acc[i][2]); v.w = gelu_f(acc[i][3]);
            *(float4*)(Xs + (e4 + i) * HDIM + h4) = v;
        }
    }
    __syncthreads();

    // ---- layer 3: K=128, no activation ----
    {
        const float4 bv = *(const float4*)(b3 + h4);
        #pragma unroll
        for (int i = 0; i < 4; ++i) { acc[i][0] = bv.x; acc[i][1] = bv.y; acc[i][2] = bv.z; acc[i][3] = bv.w; }
        tile_gemm_acc<HDIM>(W3, Xs, e4, h4, acc);
    }

    // ---- scatter: dh[src[e]] += msg (scale applied in node kernel) ----
    #pragma unroll
    for (int i = 0; i < 4; ++i) {
        const int s = edge_idx[e0 + e4 + i];   // row 0 of (2, NEDGES)
        float* dst = dh + (size_t)s * HDIM + h4;
        unsafeAtomicAdd(dst + 0, acc[i][0]);
        unsafeAtomicAdd(dst + 1, acc[i][1]);
        unsafeAtomicAdd(dst + 2, acc[i][2]);
        unsafeAtomicAdd(dst + 3, acc[i][3]);
    }
}

// ---------------------------------------------------------------------------
// Node update: x = hV + dh/30 ; h1 = LN1(x) ; y = h1 + gelu(h1@D1+b1)@D2+b2 ;
// out = LN2(y).  8 nodes per block (amortizes the 512 KB d1/d2 weight stream).
// ---------------------------------------------------------------------------
#define NT 8

__device__ __forceinline__ void ln_stats(const float* __restrict__ buf,
                                         float* __restrict__ mu_s,
                                         float* __restrict__ rs_s, int tid) {
    const int g = tid >> 5, lane = tid & 31;   // 8 groups of 32 lanes, one node each
    float s = 0.f, s2 = 0.f;
    #pragma unroll
    for (int c = lane; c < HDIM; c += 32) { const float v = buf[g * HDIM + c]; s += v; s2 += v * v; }
    #pragma unroll
    for (int off = 16; off; off >>= 1) { s += __shfl_xor(s, off, 32); s2 += __shfl_xor(s2, off, 32); }
    if (lane == 0) {
        const float m = s * (1.0f / HDIM);
        const float var = s2 * (1.0f / HDIM) - m * m;
        mu_s[g] = m;
        rs_s[g] = rsqrtf(var + LN_EPS);
    }
}

__launch_bounds__(256)
__global__ void node_update_kernel(const float* __restrict__ hV, const float* __restrict__ dh,
                                   const float* __restrict__ n1g, const float* __restrict__ n1b,
                                   const float* __restrict__ D1w, const float* __restrict__ D1b,
                                   const float* __restrict__ D2w, const float* __restrict__ D2b,
                                   const float* __restrict__ n2g, const float* __restrict__ n2b,
                                   float* __restrict__ out) {
    __shared__ float h1s[NT * HDIM];     // 4 KB: x, then h1 in place
    __shared__ float us[NT * 512];       // 16 KB: d1 activations; reused as ys
    __shared__ float vs[2 * NT * HDIM];  // 8 KB: d2 half-partials
    __shared__ float mu_s[NT], rs_s[NT];

    const int tid = threadIdx.x;
    const int n0 = blockIdx.x * NT;

    // A: x = hV + dh * (1/30)
    for (int idx = tid; idx < NT * HDIM; idx += 256) {
        const int i = idx >> 7, c = idx & 127;
        const size_t g = (size_t)(n0 + i) * HDIM + c;
        h1s[idx] = hV[g] + dh[g] * INV_SCALE;
    }
    __syncthreads();

    // B: LN1 stats
    ln_stats(h1s, mu_s, rs_s, tid);
    __syncthreads();

    // C: h1 = (x - mu) * rs * g1 + b1  (in place; each element owned by one thread)
    for (int idx = tid; idx < NT * HDIM; idx += 256) {
        const int i = idx >> 7, c = idx & 127;
        h1s[idx] = (h1s[idx] - mu_s[i]) * rs_s[i] * n1g[c] + n1b[c];
    }
    __syncthreads();

    // D: u = gelu(h1 @ D1 + b1);  thread owns outputs o=2t, 2t+1 for all 8 nodes
    {
        const int o = 2 * tid;
        const float2 bv = *(const float2*)(D1b + o);
        float a0[NT], a1[NT];
        #pragma unroll
        for (int i = 0; i < NT; ++i) { a0[i] = bv.x; a1[i] = bv.y; }
        for (int k = 0; k < HDIM; ++k) {
            const float2 w = *(const float2*)(D1w + (size_t)k * 512 + o);
            #pragma unroll
            for (int i = 0; i < NT; ++i) {
                const float xv = h1s[i * HDIM + k];
                a0[i] += xv * w.x;
                a1[i] += xv * w.y;
            }
        }
        #pragma unroll
        for (int i = 0; i < NT; ++i) {
            us[i * 512 + o]     = gelu_f(a0[i]);
            us[i * 512 + o + 1] = gelu_f(a1[i]);
        }
    }
    __syncthreads();

    // E: v = u @ D2 ;  thread owns output o = tid&127, K-half = tid>>7
    {
        const int o = tid & 127, half = tid >> 7;
        float a[NT];
        #pragma unroll
        for (int i = 0; i < NT; ++i) a[i] = 0.f;
        const int k0 = half * 256;
        for (int k = k0; k < k0 + 256; ++k) {
            const float w = D2w[(size_t)k * HDIM + o];
            #pragma unroll
            for (int i = 0; i < NT; ++i) a[i] += us[i * 512 + k] * w;
        }
        #pragma unroll
        for (int i = 0; i < NT; ++i) vs[(half * NT + i) * HDIM + o] = a[i];
    }
    __syncthreads();

    // F: y = h1 + v + b2  → into us (reused as ys)
    float* ys = us;
    for (int idx = tid; idx < NT * HDIM; idx += 256) {
        const int i = idx >> 7, c = idx & 127;
        ys[idx] = h1s[idx] + vs[i * HDIM + c] + vs[(NT + i) * HDIM + c] + D2b[c];
    }
    __syncthreads();

    // G: LN2 stats
    ln_stats(ys, mu_s, rs_s, tid);
    __syncthreads();

    // H: out = (y - mu) * rs * g2 + b2
    for (int idx = tid; idx < NT * HDIM; idx += 256) {
        const int i = idx >> 7, c = idx & 127;
        out[(size_t)(n0 + i) * HDIM + c] = (ys[idx] - mu_s[i]) * rs_s[i] * n2g[c] + n2b[c];
    }
}

extern "C" void kernel_launch(void* const* d_in, const int* in_sizes, int n_in,
                              void* d_out, int out_size, void* d_ws, size_t ws_size,
                              hipStream_t stream) {
    const float* hV  = (const float*)d_in[0];
    const float* hE  = (const float*)d_in[1];
    const int*  eidx = (const int*)d_in[2];
    const float* W1w = (const float*)d_in[3];
    const float* W1b = (const float*)d_in[4];
    const float* W2w = (const float*)d_in[5];
    const float* W2b = (const float*)d_in[6];
    const float* W3w = (const float*)d_in[7];
    const float* W3b = (const float*)d_in[8];
    const float* n1g = (const float*)d_in[9];
    const float* n1b = (const float*)d_in[10];
    const float* D1w = (const float*)d_in[11];
    const float* D1b = (const float*)d_in[12];
    const float* D2w = (const float*)d_in[13];
    const float* D2b = (const float*)d_in[14];
    const float* n2g = (const float*)d_in[15];
    const float* n2b = (const float*)d_in[16];
    float* out = (float*)d_out;
    float* dh  = (float*)d_ws;   // 20000*128 fp32 accumulator

    hipMemsetAsync(dh, 0, (size_t)NNODES * HDIM * sizeof(float), stream);
    edge_mlp_kernel<<<NEDGES / 32, 256, 0, stream>>>(hE, eidx, W1w, W1b, W2w, W2b, W3w, W3b, dh);
    node_update_kernel<<<NNODES / NT, 256, 0, stream>>>(hV, dh, n1g, n1b, D1w, D1b, D2w, D2b, n2g, n2b, out);
}

// Round 2
// 775.943 us; speedup vs baseline: 1.7208x; 1.7208x over previous
//
#include <hip/hip_runtime.h>
#include <hip/hip_bf16.h>
#include <math.h>

#define NNODES 20000
#define NEDGES 320000
#define HDIM   128
#define INDIM  256
#define INV_SCALE (1.0f/30.0f)
#define LN_EPS 1e-5f

typedef __bf16 bf16x8 __attribute__((ext_vector_type(8)));
typedef float  f32x4  __attribute__((ext_vector_type(4)));
typedef unsigned short ushort_t;

__device__ __forceinline__ float gelu_f(float x) {
    return 0.5f * x * (1.0f + erff(x * 0.7071067811865476f));
}

__device__ __forceinline__ unsigned short f2bf(float f) {
    union { __hip_bfloat16 h; unsigned short u; } c;
    c.h = __float2bfloat16(f);
    return c.u;
}

// ---------------------------------------------------------------------------
// Weight prep: convert W1/W2/W3 to bf16, swizzled into exact B-fragment order
// for mfma_f32_16x16x32_bf16: frag (s,t) lane L element j holds
// W[k = s*32 + (L>>4)*8 + j][n = t*16 + (L&15)], stored contiguously so each
// lane's 8 bf16 = one 16B global_load_dwordx4.
//   layout: Wsw[ base + ((s*8 + t)*64 + L)*8 + j ]
//   bases (elements): W1=0 (32768), W2=32768 (16384), W3=49152 (16384)
// ---------------------------------------------------------------------------
__global__ void prep_weights(const float* __restrict__ W1,
                             const float* __restrict__ W2,
                             const float* __restrict__ W3,
                             ushort_t* __restrict__ Wsw) {
    const int id = blockIdx.x * 256 + threadIdx.x;   // 0..65535
    const float* W; int base, idx;
    if (id < 32768)      { W = W1; base = 0;     idx = id; }
    else if (id < 49152) { W = W2; base = 32768; idx = id - 32768; }
    else                 { W = W3; base = 49152; idx = id - 49152; }
    const int j = idx & 7, lane = (idx >> 3) & 63, t = (idx >> 9) & 7, s = idx >> 12;
    const int k = s * 32 + (lane >> 4) * 8 + j;
    const int n = t * 16 + (lane & 15);
    Wsw[base + idx] = f2bf(W[k * HDIM + n]);
}

// ---------------------------------------------------------------------------
// Edge MLP via MFMA. Block = 64 edges, 4 waves; wave owns 16 edges x 128 ch.
// ---------------------------------------------------------------------------
#define ETILE 64
#define SA 264   // A1 row stride (bf16 elems): 256 + 8 pad, keeps 16B align
#define SY 136   // A2 row stride: 128 + 8 pad

template<int KSTEPS, int STRIDE>
__device__ __forceinline__ void mfma_layer(const ushort_t* __restrict__ Ain,   // wave's 16-row base
                                           const ushort_t* __restrict__ Wsw,   // layer fragment base
                                           const float* __restrict__ bias,
                                           int lane, f32x4* acc) {
    const int quad = lane >> 4, l16 = lane & 15;
    #pragma unroll
    for (int t = 0; t < 8; ++t) {
        const float b = bias[t * 16 + l16];           // D[row][n] += b[n]
        acc[t] = (f32x4){b, b, b, b};
    }
    const ushort_t* arow = Ain + l16 * STRIDE + quad * 8;
    #pragma unroll
    for (int s = 0; s < KSTEPS; ++s) {
        const bf16x8 a = *(const bf16x8*)(arow + s * 32);
        #pragma unroll
        for (int t = 0; t < 8; ++t) {
            const bf16x8 b = *(const bf16x8*)(Wsw + (size_t)((s * 8 + t) * 64 + lane) * 8);
            acc[t] = __builtin_amdgcn_mfma_f32_16x16x32_bf16(a, b, acc[t], 0, 0, 0);
        }
    }
}

__device__ __forceinline__ void store_gelu(ushort_t* __restrict__ Yout,  // wave's 16-row base
                                           int lane, const f32x4* acc) {
    const int quad = lane >> 4, l16 = lane & 15;
    #pragma unroll
    for (int t = 0; t < 8; ++t)
        #pragma unroll
        for (int r = 0; r < 4; ++r)
            Yout[(quad * 4 + r) * SY + t * 16 + l16] = f2bf(gelu_f(acc[t][r]));
}

__launch_bounds__(256)
__global__ void edge_mlp_mfma(const float* __restrict__ hE,
                              const int* __restrict__ edge_idx,
                              const ushort_t* __restrict__ Wsw,
                              const float* __restrict__ b1,
                              const float* __restrict__ b2,
                              const float* __restrict__ b3,
                              float* __restrict__ dh) {
    __shared__ ushort_t A1[ETILE * SA];   // 33792 B: bf16 h_E tile
    __shared__ ushort_t A2[ETILE * SY];   // 17408 B: inter-layer activations

    const int tid = threadIdx.x;
    const size_t e0 = (size_t)blockIdx.x * ETILE;

    // stage 64 edges of h_E: fp32 -> bf16 -> LDS (row stride SA)
    {
        const float4* src = (const float4*)(hE + e0 * INDIM);
        #pragma unroll
        for (int it = 0; it < 16; ++it) {
            const int f4 = it * 256 + tid;            // float4 index in 64x256 tile
            const int row = f4 >> 6;
            const int col = (f4 & 63) << 2;
            const float4 v = src[f4];
            ushort4 u;
            u.x = f2bf(v.x); u.y = f2bf(v.y); u.z = f2bf(v.z); u.w = f2bf(v.w);
            *(ushort4*)(A1 + row * SA + col) = u;
        }
    }
    __syncthreads();

    const int lane = tid & 63, wave = tid >> 6;
    const int quad = lane >> 4, l16 = lane & 15;
    f32x4 acc[8];

    // layer 1: [16x256] x [256x128], gelu
    mfma_layer<8, SA>(A1 + wave * 16 * SA, Wsw, b1, lane, acc);
    store_gelu(A2 + wave * 16 * SY, lane, acc);
    __syncthreads();

    // layer 2: [16x128] x [128x128], gelu (in-place: reads complete before writes)
    mfma_layer<4, SY>(A2 + wave * 16 * SY, Wsw + 32768, b2, lane, acc);
    store_gelu(A2 + wave * 16 * SY, lane, acc);
    __syncthreads();

    // layer 3: [16x128] x [128x128], no activation
    mfma_layer<4, SY>(A2 + wave * 16 * SY, Wsw + 49152, b3, lane, acc);

    // scatter: acc[t][r] = msg[edge row quad*4+r][channel t*16+l16]
    #pragma unroll
    for (int r = 0; r < 4; ++r) {
        const int e = (int)e0 + wave * 16 + quad * 4 + r;
        const int s = edge_idx[e];
        float* dst = dh + (size_t)s * HDIM + l16;
        #pragma unroll
        for (int t = 0; t < 8; ++t)
            unsafeAtomicAdd(dst + t * 16, acc[t][r]);
    }
}

// ---------------------------------------------------------------------------
// Node update (unchanged from round 1): x = hV + dh/30; LN1; FFN; LN2
// ---------------------------------------------------------------------------
#define NT 8

__device__ __forceinline__ void ln_stats(const float* __restrict__ buf,
                                         float* __restrict__ mu_s,
                                         float* __restrict__ rs_s, int tid) {
    const int g = tid >> 5, lane = tid & 31;
    float s = 0.f, s2 = 0.f;
    #pragma unroll
    for (int c = lane; c < HDIM; c += 32) { const float v = buf[g * HDIM + c]; s += v; s2 += v * v; }
    #pragma unroll
    for (int off = 16; off; off >>= 1) { s += __shfl_xor(s, off, 32); s2 += __shfl_xor(s2, off, 32); }
    if (lane == 0) {
        const float m = s * (1.0f / HDIM);
        const float var = s2 * (1.0f / HDIM) - m * m;
        mu_s[g] = m;
        rs_s[g] = rsqrtf(var + LN_EPS);
    }
}

__launch_bounds__(256)
__global__ void node_update_kernel(const float* __restrict__ hV, const float* __restrict__ dh,
                                   const float* __restrict__ n1g, const float* __restrict__ n1b,
                                   const float* __restrict__ D1w, const float* __restrict__ D1b,
                                   const float* __restrict__ D2w, const float* __restrict__ D2b,
                                   const float* __restrict__ n2g, const float* __restrict__ n2b,
                                   float* __restrict__ out) {
    __shared__ float h1s[NT * HDIM];
    __shared__ float us[NT * 512];
    __shared__ float vs[2 * NT * HDIM];
    __shared__ float mu_s[NT], rs_s[NT];

    const int tid = threadIdx.x;
    const int n0 = blockIdx.x * NT;

    for (int idx = tid; idx < NT * HDIM; idx += 256) {
        const int i = idx >> 7, c = idx & 127;
        const size_t g = (size_t)(n0 + i) * HDIM + c;
        h1s[idx] = hV[g] + dh[g] * INV_SCALE;
    }
    __syncthreads();

    ln_stats(h1s, mu_s, rs_s, tid);
    __syncthreads();

    for (int idx = tid; idx < NT * HDIM; idx += 256) {
        const int i = idx >> 7, c = idx & 127;
        h1s[idx] = (h1s[idx] - mu_s[i]) * rs_s[i] * n1g[c] + n1b[c];
    }
    __syncthreads();

    {
        const int o = 2 * tid;
        const float2 bv = *(const float2*)(D1b + o);
        float a0[NT], a1[NT];
        #pragma unroll
        for (int i = 0; i < NT; ++i) { a0[i] = bv.x; a1[i] = bv.y; }
        for (int k = 0; k < HDIM; ++k) {
            const float2 w = *(const float2*)(D1w + (size_t)k * 512 + o);
            #pragma unroll
            for (int i = 0; i < NT; ++i) {
                const float xv = h1s[i * HDIM + k];
                a0[i] += xv * w.x;
                a1[i] += xv * w.y;
            }
        }
        #pragma unroll
        for (int i = 0; i < NT; ++i) {
            us[i * 512 + o]     = gelu_f(a0[i]);
            us[i * 512 + o + 1] = gelu_f(a1[i]);
        }
    }
    __syncthreads();

    {
        const int o = tid & 127, half = tid >> 7;
        float a[NT];
        #pragma unroll
        for (int i = 0; i < NT; ++i) a[i] = 0.f;
        const int k0 = half * 256;
        for (int k = k0; k < k0 + 256; ++k) {
            const float w = D2w[(size_t)k * HDIM + o];
            #pragma unroll
            for (int i = 0; i < NT; ++i) a[i] += us[i * 512 + k] * w;
        }
        #pragma unroll
        for (int i = 0; i < NT; ++i) vs[(half * NT + i) * HDIM + o] = a[i];
    }
    __syncthreads();

    float* ys = us;
    for (int idx = tid; idx < NT * HDIM; idx += 256) {
        const int i = idx >> 7, c = idx & 127;
        ys[idx] = h1s[idx] + vs[i * HDIM + c] + vs[(NT + i) * HDIM + c] + D2b[c];
    }
    __syncthreads();

    ln_stats(ys, mu_s, rs_s, tid);
    __syncthreads();

    for (int idx = tid; idx < NT * HDIM; idx += 256) {
        const int i = idx >> 7, c = idx & 127;
        out[(size_t)(n0 + i) * HDIM + c] = (ys[idx] - mu_s[i]) * rs_s[i] * n2g[c] + n2b[c];
    }
}

extern "C" void kernel_launch(void* const* d_in, const int* in_sizes, int n_in,
                              void* d_out, int out_size, void* d_ws, size_t ws_size,
                              hipStream_t stream) {
    const float* hV  = (const float*)d_in[0];
    const float* hE  = (const float*)d_in[1];
    const int*  eidx = (const int*)d_in[2];
    const float* W1w = (const float*)d_in[3];
    const float* W1b = (const float*)d_in[4];
    const float* W2w = (const float*)d_in[5];
    const float* W2b = (const float*)d_in[6];
    const float* W3w = (const float*)d_in[7];
    const float* W3b = (const float*)d_in[8];
    const float* n1g = (const float*)d_in[9];
    const float* n1b = (const float*)d_in[10];
    const float* D1w = (const float*)d_in[11];
    const float* D1b = (const float*)d_in[12];
    const float* D2w = (const float*)d_in[13];
    const float* D2b = (const float*)d_in[14];
    const float* n2g = (const float*)d_in[15];
    const float* n2b = (const float*)d_in[16];
    float* out = (float*)d_out;
    float* dh  = (float*)d_ws;   // 20000*128 fp32 accumulator (10.24 MB, known to fit)

    // Swizzled bf16 weights (131072 B) live in the TAIL of d_out: the node
    // kernel rewrites every element of d_out afterwards, and stream ordering
    // guarantees the edge kernel is done reading them before that.
    ushort_t* Wsw = (ushort_t*)((char*)d_out + (size_t)NNODES * HDIM * 4 - 131072);

    hipMemsetAsync(dh, 0, (size_t)NNODES * HDIM * sizeof(float), stream);
    prep_weights<<<256, 256, 0, stream>>>(W1w, W2w, W3w, Wsw);
    edge_mlp_mfma<<<NEDGES / ETILE, 256, 0, stream>>>(hE, eidx, Wsw, W1b, W2b, W3b, dh);
    node_update_kernel<<<NNODES / NT, 256, 0, stream>>>(hV, dh, n1g, n1b, D1w, D1b, D2w, D2b, n2g, n2b, out);
}

// Round 3
// 663.948 us; speedup vs baseline: 2.0111x; 1.1687x over previous
//
#include <hip/hip_runtime.h>
#include <hip/hip_bf16.h>
#include <math.h>

#define NNODES 20000
#define NEDGES 320000
#define HDIM   128
#define INDIM  256
#define INV_SCALE (1.0f/30.0f)
#define LN_EPS 1e-5f

typedef __bf16 bf16x8 __attribute__((ext_vector_type(8)));
typedef float  f32x4  __attribute__((ext_vector_type(4)));
typedef unsigned short ushort_t;

__device__ __forceinline__ unsigned short f2bf(float f) {
    union { __hip_bfloat16 h; unsigned short u; } c;
    c.h = __float2bfloat16(f);
    return c.u;
}

// Fast gelu: x * sigmoid(1.5957691*x + 0.0713548*x^3)  (tanh-form, max |err| ~1e-3,
// well under the 0.095 absmax budget; erff was ~30 VALU instrs, this is ~7)
__device__ __forceinline__ float gelu_fast(float x) {
    const float z = x * (1.595769122f + 0.071354816f * x * x);
    return x / (1.0f + __expf(-z));
}

__device__ __forceinline__ f32x4 mfma_bf16(bf16x8 a, bf16x8 b, f32x4 c) {
    return __builtin_amdgcn_mfma_f32_16x16x32_bf16(a, b, c, 0, 0, 0);
}

// ---------------------------------------------------------------------------
// Weight prep. B-fragment order for mfma_f32_16x16x32_bf16: frag (s,t), lane L,
// elem j holds W[k = s*32 + (L>>4)*8 + j][n = t*16 + (L&15)]; each lane's 8 bf16
// are contiguous (one 16B load). Fragment f stored at Wsw[(f*64 + L)*8 + j].
// Edge weights: W1 f=s*8+t (base 0), W2 (base 32768), W3 (base 49152).
// ---------------------------------------------------------------------------
__global__ void prep_edge_weights(const float* __restrict__ W1,
                                  const float* __restrict__ W2,
                                  const float* __restrict__ W3,
                                  ushort_t* __restrict__ Wsw) {
    const int id = blockIdx.x * 256 + threadIdx.x;   // 0..65535
    const float* W; int base, idx;
    if (id < 32768)      { W = W1; base = 0;     idx = id; }
    else if (id < 49152) { W = W2; base = 32768; idx = id - 32768; }
    else                 { W = W3; base = 49152; idx = id - 49152; }
    const int j = idx & 7, lane = (idx >> 3) & 63, t = (idx >> 9) & 7, s = idx >> 12;
    const int k = s * 32 + (lane >> 4) * 8 + j;
    const int n = t * 16 + (lane & 15);
    Wsw[base + idx] = f2bf(W[k * HDIM + n]);
}

// Node weights: D1 (128x512): f = s*32+t (s<4, t<32). D2 (512x128): f = s*8+t (s<16, t<8).
__global__ void prep_node_weights(const float* __restrict__ D1,
                                  const float* __restrict__ D2,
                                  ushort_t* __restrict__ D1sw,
                                  ushort_t* __restrict__ D2sw) {
    const int id = blockIdx.x * 256 + threadIdx.x;   // 0..131071
    if (id < 65536) {
        const int idx = id;
        const int j = idx & 7, lane = (idx >> 3) & 63, f = idx >> 9;   // f = s*32+t
        const int t = f & 31, s = f >> 5;
        const int k = s * 32 + (lane >> 4) * 8 + j;
        const int n = t * 16 + (lane & 15);
        D1sw[idx] = f2bf(D1[k * 512 + n]);
    } else {
        const int idx = id - 65536;
        const int j = idx & 7, lane = (idx >> 3) & 63, f = idx >> 9;   // f = s*8+t
        const int t = f & 7, s = f >> 3;
        const int k = s * 32 + (lane >> 4) * 8 + j;
        const int n = t * 16 + (lane & 15);
        D2sw[idx] = f2bf(D2[k * HDIM + n]);
    }
}

// ---------------------------------------------------------------------------
// Edge MLP via MFMA. Block = 128 edges, 4 waves; wave owns 32 edges (2 row-
// tiles) x 128 ch. No A1 staging (each h_E row used by exactly one wave —
// direct global->reg->bf16). Per-wave A2 regions -> ZERO barriers.
// LDS 34.8 KB -> 4 blocks/CU.
// ---------------------------------------------------------------------------
#define SY 136   // A2 row stride (bf16): 128 + 8 pad (272B: bank offset 4 -> 2-way, free)

__launch_bounds__(256, 4)
__global__ void edge_mlp_mfma(const float* __restrict__ hE,
                              const int* __restrict__ edge_idx,
                              const ushort_t* __restrict__ Wsw,
                              const float* __restrict__ b1,
                              const float* __restrict__ b2,
                              const float* __restrict__ b3,
                              float* __restrict__ dh) {
    __shared__ ushort_t A2[4][32 * SY];   // 34816 B total, per-wave regions

    const int tid = threadIdx.x;
    const int wave = tid >> 6, lane = tid & 63;
    const int quad = lane >> 4, l16 = lane & 15;
    const size_t e0 = (size_t)blockIdx.x * 128 + wave * 32;
    ushort_t* Aw = A2[wave];

    f32x4 acc[2][8];

    // ---- layer 1: [32x256] x [256x128], A direct from global ----
    #pragma unroll
    for (int t = 0; t < 8; ++t) {
        const float bv = b1[t * 16 + l16];
        acc[0][t] = (f32x4){bv, bv, bv, bv};
        acc[1][t] = acc[0][t];
    }
    #pragma unroll
    for (int s = 0; s < 8; ++s) {
        bf16x8 a[2];
        #pragma unroll
        for (int rt = 0; rt < 2; ++rt) {
            const float4* p = (const float4*)(hE + (e0 + rt * 16 + l16) * INDIM + s * 32 + quad * 8);
            const float4 v0 = p[0], v1 = p[1];
            union { bf16x8 v; ushort_t u[8]; } c;
            c.u[0] = f2bf(v0.x); c.u[1] = f2bf(v0.y); c.u[2] = f2bf(v0.z); c.u[3] = f2bf(v0.w);
            c.u[4] = f2bf(v1.x); c.u[5] = f2bf(v1.y); c.u[6] = f2bf(v1.z); c.u[7] = f2bf(v1.w);
            a[rt] = c.v;
        }
        #pragma unroll
        for (int t = 0; t < 8; ++t) {
            const bf16x8 b = *(const bf16x8*)(Wsw + (size_t)((s * 8 + t) * 64 + lane) * 8);
            acc[0][t] = mfma_bf16(a[0], b, acc[0][t]);
            acc[1][t] = mfma_bf16(a[1], b, acc[1][t]);
        }
    }
    #pragma unroll
    for (int rt = 0; rt < 2; ++rt)
        #pragma unroll
        for (int t = 0; t < 8; ++t)
            #pragma unroll
            for (int r = 0; r < 4; ++r)
                Aw[(rt * 16 + quad * 4 + r) * SY + t * 16 + l16] = f2bf(gelu_fast(acc[rt][t][r]));

    // ---- layer 2: [32x128] x [128x128] (in-place: all reads precede writes) ----
    #pragma unroll
    for (int t = 0; t < 8; ++t) {
        const float bv = b2[t * 16 + l16];
        acc[0][t] = (f32x4){bv, bv, bv, bv};
        acc[1][t] = acc[0][t];
    }
    #pragma unroll
    for (int s = 0; s < 4; ++s) {
        bf16x8 a[2];
        #pragma unroll
        for (int rt = 0; rt < 2; ++rt)
            a[rt] = *(const bf16x8*)(Aw + (rt * 16 + l16) * SY + s * 32 + quad * 8);
        #pragma unroll
        for (int t = 0; t < 8; ++t) {
            const bf16x8 b = *(const bf16x8*)(Wsw + 32768 + (size_t)((s * 8 + t) * 64 + lane) * 8);
            acc[0][t] = mfma_bf16(a[0], b, acc[0][t]);
            acc[1][t] = mfma_bf16(a[1], b, acc[1][t]);
        }
    }
    #pragma unroll
    for (int rt = 0; rt < 2; ++rt)
        #pragma unroll
        for (int t = 0; t < 8; ++t)
            #pragma unroll
            for (int r = 0; r < 4; ++r)
                Aw[(rt * 16 + quad * 4 + r) * SY + t * 16 + l16] = f2bf(gelu_fast(acc[rt][t][r]));

    // ---- layer 3: [32x128] x [128x128], no activation ----
    #pragma unroll
    for (int t = 0; t < 8; ++t) {
        const float bv = b3[t * 16 + l16];
        acc[0][t] = (f32x4){bv, bv, bv, bv};
        acc[1][t] = acc[0][t];
    }
    #pragma unroll
    for (int s = 0; s < 4; ++s) {
        bf16x8 a[2];
        #pragma unroll
        for (int rt = 0; rt < 2; ++rt)
            a[rt] = *(const bf16x8*)(Aw + (rt * 16 + l16) * SY + s * 32 + quad * 8);
        #pragma unroll
        for (int t = 0; t < 8; ++t) {
            const bf16x8 b = *(const bf16x8*)(Wsw + 49152 + (size_t)((s * 8 + t) * 64 + lane) * 8);
            acc[0][t] = mfma_bf16(a[0], b, acc[0][t]);
            acc[1][t] = mfma_bf16(a[1], b, acc[1][t]);
        }
    }

    // ---- scatter ----
    #pragma unroll
    for (int rt = 0; rt < 2; ++rt)
        #pragma unroll
        for (int r = 0; r < 4; ++r) {
            const int e = (int)e0 + rt * 16 + quad * 4 + r;
            const int s = edge_idx[e];
            float* dst = dh + (size_t)s * HDIM + l16;
            #pragma unroll
            for (int t = 0; t < 8; ++t)
                unsafeAtomicAdd(dst + t * 16, acc[rt][t][r]);
        }
}

// ---------------------------------------------------------------------------
// Node update via MFMA. Block = 32 nodes, 4 waves. LN in fp32; FFN in bf16.
// Wave w handles ALL 32 rows for an N-slice, so each weight fragment is read
// exactly once per block. LDS 58.6 KB -> 2 blocks/CU. 625 blocks.
// ---------------------------------------------------------------------------
__launch_bounds__(256)
__global__ void node_mfma(const float* __restrict__ hV, const float* __restrict__ dh,
                          const float* __restrict__ n1g, const float* __restrict__ n1b,
                          const ushort_t* __restrict__ D1sw, const float* __restrict__ D1b,
                          const ushort_t* __restrict__ D2sw, const float* __restrict__ D2b,
                          const float* __restrict__ n2g, const float* __restrict__ n2b,
                          float* __restrict__ out) {
    __shared__ __align__(16) float xs[32 * HDIM];      // 16 KB fp32 x (kept for residual)
    __shared__ __align__(16) ushort_t h1a[32 * SY];    // 8.7 KB bf16 h1, A-layout
    __shared__ __align__(16) ushort_t ua[32 * 520];    // 33.3 KB bf16 u, A-layout; reused as fp32 y
    __shared__ float mu_s[32], rs_s[32];

    const int tid = threadIdx.x;
    const int wave = tid >> 6, lane = tid & 63;
    const int quad = lane >> 4, l16 = lane & 15;
    const int n0 = blockIdx.x * 32;

    // 1: x = hV + dh/30
    #pragma unroll
    for (int it = 0; it < 4; ++it) {
        const int f4 = it * 256 + tid;   // 0..1023
        const float4 hv = ((const float4*)(hV + (size_t)n0 * HDIM))[f4];
        const float4 dv = ((const float4*)(dh + (size_t)n0 * HDIM))[f4];
        ((float4*)xs)[f4] = (float4){hv.x + dv.x * INV_SCALE, hv.y + dv.y * INV_SCALE,
                                     hv.z + dv.z * INV_SCALE, hv.w + dv.w * INV_SCALE};
    }
    __syncthreads();

    // 2: LN1 stats (8 threads/row, 16 cols each, shfl within 8-lane groups)
    {
        const int row = tid >> 3, q = tid & 7;
        float s = 0.f, s2 = 0.f;
        #pragma unroll
        for (int c = 0; c < 16; ++c) { const float v = xs[row * HDIM + q * 16 + c]; s += v; s2 += v * v; }
        #pragma unroll
        for (int off = 1; off < 8; off <<= 1) { s += __shfl_xor(s, off); s2 += __shfl_xor(s2, off); }
        if (q == 0) {
            const float m = s * (1.0f / HDIM);
            mu_s[row] = m;
            rs_s[row] = rsqrtf(s2 * (1.0f / HDIM) - m * m + LN_EPS);
        }
    }
    __syncthreads();

    // 3: h1 (bf16, A-layout, stride SY)
    #pragma unroll
    for (int it = 0; it < 2; ++it) {
        const int g = it * 256 + tid;        // 512 groups of 8 cols
        const int row = g >> 4, col = (g & 15) * 8;
        const float mu = mu_s[row], rs = rs_s[row];
        union { bf16x8 v; ushort_t u[8]; } c;
        #pragma unroll
        for (int j = 0; j < 8; ++j) {
            const float h1 = (xs[row * HDIM + col + j] - mu) * rs * n1g[col + j] + n1b[col + j];
            c.u[j] = f2bf(h1);
        }
        *(bf16x8*)(h1a + row * SY + col) = c.v;
    }
    __syncthreads();

    // 4: u = gelu(h1 @ D1 + b1); wave w: all 32 rows (2 rowtiles) x N slice w*128..
    {
        f32x4 acc1[2][8];
        #pragma unroll
        for (int t = 0; t < 8; ++t) {
            const float bv = D1b[wave * 128 + t * 16 + l16];
            acc1[0][t] = (f32x4){bv, bv, bv, bv};
            acc1[1][t] = acc1[0][t];
        }
        #pragma unroll
        for (int s = 0; s < 4; ++s) {
            bf16x8 a[2];
            #pragma unroll
            for (int rt = 0; rt < 2; ++rt)
                a[rt] = *(const bf16x8*)(h1a + (rt * 16 + l16) * SY + s * 32 + quad * 8);
            #pragma unroll
            for (int t = 0; t < 8; ++t) {
                const bf16x8 b = *(const bf16x8*)(D1sw + (size_t)((s * 32 + wave * 8 + t) * 64 + lane) * 8);
                acc1[0][t] = mfma_bf16(a[0], b, acc1[0][t]);
                acc1[1][t] = mfma_bf16(a[1], b, acc1[1][t]);
            }
        }
        // 5: gelu -> ua (bf16, stride 520)
        #pragma unroll
        for (int rt = 0; rt < 2; ++rt)
            #pragma unroll
            for (int t = 0; t < 8; ++t)
                #pragma unroll
                for (int r = 0; r < 4; ++r)
                    ua[(rt * 16 + quad * 4 + r) * 520 + wave * 128 + t * 16 + l16] =
                        f2bf(gelu_fast(acc1[rt][t][r]));
    }
    __syncthreads();

    // 6: v = u @ D2; wave w: all 32 rows x N slice w*32.. (2 coltiles)
    f32x4 acc2[2][2];
    acc2[0][0] = (f32x4){0,0,0,0}; acc2[0][1] = acc2[0][0];
    acc2[1][0] = acc2[0][0];       acc2[1][1] = acc2[0][0];
    #pragma unroll
    for (int s = 0; s < 16; ++s) {
        bf16x8 a[2];
        #pragma unroll
        for (int rt = 0; rt < 2; ++rt)
            a[rt] = *(const bf16x8*)(ua + (rt * 16 + l16) * 520 + s * 32 + quad * 8);
        #pragma unroll
        for (int tt = 0; tt < 2; ++tt) {
            const bf16x8 b = *(const bf16x8*)(D2sw + (size_t)((s * 8 + wave * 2 + tt) * 64 + lane) * 8);
            acc2[0][tt] = mfma_bf16(a[0], b, acc2[0][tt]);
            acc2[1][tt] = mfma_bf16(a[1], b, acc2[1][tt]);
        }
    }
    __syncthreads();   // all ua reads done before yf aliases it

    // 7: y = h1 + v + b2 (fp32), into yf (aliases ua)
    float* yf = (float*)ua;
    #pragma unroll
    for (int rt = 0; rt < 2; ++rt)
        #pragma unroll
        for (int tt = 0; tt < 2; ++tt)
            #pragma unroll
            for (int r = 0; r < 4; ++r) {
                const int row = rt * 16 + quad * 4 + r;
                const int col = wave * 32 + tt * 16 + l16;
                const float h1 = (xs[row * HDIM + col] - mu_s[row]) * rs_s[row] * n1g[col] + n1b[col];
                yf[row * HDIM + col] = h1 + acc2[rt][tt][r] + D2b[col];
            }
    __syncthreads();

    // 8: LN2 stats (reuse mu_s/rs_s — all prior reads completed at barrier)
    {
        const int row = tid >> 3, q = tid & 7;
        float s = 0.f, s2 = 0.f;
        #pragma unroll
        for (int c = 0; c < 16; ++c) { const float v = yf[row * HDIM + q * 16 + c]; s += v; s2 += v * v; }
        #pragma unroll
        for (int off = 1; off < 8; off <<= 1) { s += __shfl_xor(s, off); s2 += __shfl_xor(s2, off); }
        if (q == 0) {
            const float m = s * (1.0f / HDIM);
            mu_s[row] = m;
            rs_s[row] = rsqrtf(s2 * (1.0f / HDIM) - m * m + LN_EPS);
        }
    }
    __syncthreads();

    // 9: out = LN2(y)
    #pragma unroll
    for (int it = 0; it < 4; ++it) {
        const int f4 = it * 256 + tid;
        const int row = f4 >> 5, col = (f4 & 31) * 4;
        const float4 y = ((const float4*)yf)[f4];
        const float mu = mu_s[row], rs = rs_s[row];
        float4 o;
        o.x = (y.x - mu) * rs * n2g[col + 0] + n2b[col + 0];
        o.y = (y.y - mu) * rs * n2g[col + 1] + n2b[col + 1];
        o.z = (y.z - mu) * rs * n2g[col + 2] + n2b[col + 2];
        o.w = (y.w - mu) * rs * n2g[col + 3] + n2b[col + 3];
        ((float4*)(out + (size_t)n0 * HDIM))[f4] = o;
    }
}

// ---------------------------------------------------------------------------
// Fallback fp32 node kernel (used only if ws_size can't hold node weights)
// ---------------------------------------------------------------------------
#define NT 8
__device__ __forceinline__ void ln_stats32(const float* __restrict__ buf,
                                           float* __restrict__ mu_s,
                                           float* __restrict__ rs_s, int tid) {
    const int g = tid >> 5, lane = tid & 31;
    float s = 0.f, s2 = 0.f;
    #pragma unroll
    for (int c = lane; c < HDIM; c += 32) { const float v = buf[g * HDIM + c]; s += v; s2 += v * v; }
    #pragma unroll
    for (int off = 16; off; off >>= 1) { s += __shfl_xor(s, off, 32); s2 += __shfl_xor(s2, off, 32); }
    if (lane == 0) {
        const float m = s * (1.0f / HDIM);
        mu_s[g] = m;
        rs_s[g] = rsqrtf(s2 * (1.0f / HDIM) - m * m + LN_EPS);
    }
}

__launch_bounds__(256)
__global__ void node_update_f32(const float* __restrict__ hV, const float* __restrict__ dh,
                                const float* __restrict__ n1g, const float* __restrict__ n1b,
                                const float* __restrict__ D1w, const float* __restrict__ D1b,
                                const float* __restrict__ D2w, const float* __restrict__ D2b,
                                const float* __restrict__ n2g, const float* __restrict__ n2b,
                                float* __restrict__ out) {
    __shared__ float h1s[NT * HDIM];
    __shared__ float us[NT * 512];
    __shared__ float vs[2 * NT * HDIM];
    __shared__ float mu_s[NT], rs_s[NT];
    const int tid = threadIdx.x;
    const int n0 = blockIdx.x * NT;
    for (int idx = tid; idx < NT * HDIM; idx += 256) {
        const int i = idx >> 7, c = idx & 127;
        const size_t g = (size_t)(n0 + i) * HDIM + c;
        h1s[idx] = hV[g] + dh[g] * INV_SCALE;
    }
    __syncthreads();
    ln_stats32(h1s, mu_s, rs_s, tid);
    __syncthreads();
    for (int idx = tid; idx < NT * HDIM; idx += 256) {
        const int i = idx >> 7, c = idx & 127;
        h1s[idx] = (h1s[idx] - mu_s[i]) * rs_s[i] * n1g[c] + n1b[c];
    }
    __syncthreads();
    {
        const int o = 2 * tid;
        const float2 bv = *(const float2*)(D1b + o);
        float a0[NT], a1[NT];
        #pragma unroll
        for (int i = 0; i < NT; ++i) { a0[i] = bv.x; a1[i] = bv.y; }
        for (int k = 0; k < HDIM; ++k) {
            const float2 w = *(const float2*)(D1w + (size_t)k * 512 + o);
            #pragma unroll
            for (int i = 0; i < NT; ++i) {
                const float xv = h1s[i * HDIM + k];
                a0[i] += xv * w.x; a1[i] += xv * w.y;
            }
        }
        #pragma unroll
        for (int i = 0; i < NT; ++i) {
            us[i * 512 + o]     = gelu_fast(a0[i]);
            us[i * 512 + o + 1] = gelu_fast(a1[i]);
        }
    }
    __syncthreads();
    {
        const int o = tid & 127, half = tid >> 7;
        float a[NT];
        #pragma unroll
        for (int i = 0; i < NT; ++i) a[i] = 0.f;
        const int k0 = half * 256;
        for (int k = k0; k < k0 + 256; ++k) {
            const float w = D2w[(size_t)k * HDIM + o];
            #pragma unroll
            for (int i = 0; i < NT; ++i) a[i] += us[i * 512 + k] * w;
        }
        #pragma unroll
        for (int i = 0; i < NT; ++i) vs[(half * NT + i) * HDIM + o] = a[i];
    }
    __syncthreads();
    float* ys = us;
    for (int idx = tid; idx < NT * HDIM; idx += 256) {
        const int i = idx >> 7, c = idx & 127;
        ys[idx] = h1s[idx] + vs[i * HDIM + c] + vs[(NT + i) * HDIM + c] + D2b[c];
    }
    __syncthreads();
    ln_stats32(ys, mu_s, rs_s, tid);
    __syncthreads();
    for (int idx = tid; idx < NT * HDIM; idx += 256) {
        const int i = idx >> 7, c = idx & 127;
        out[(size_t)(n0 + i) * HDIM + c] = (ys[idx] - mu_s[i]) * rs_s[i] * n2g[c] + n2b[c];
    }
}

extern "C" void kernel_launch(void* const* d_in, const int* in_sizes, int n_in,
                              void* d_out, int out_size, void* d_ws, size_t ws_size,
                              hipStream_t stream) {
    const float* hV  = (const float*)d_in[0];
    const float* hE  = (const float*)d_in[1];
    const int*  eidx = (const int*)d_in[2];
    const float* W1w = (const float*)d_in[3];
    const float* W1b = (const float*)d_in[4];
    const float* W2w = (const float*)d_in[5];
    const float* W2b = (const float*)d_in[6];
    const float* W3w = (const float*)d_in[7];
    const float* W3b = (const float*)d_in[8];
    const float* n1g = (const float*)d_in[9];
    const float* n1b = (const float*)d_in[10];
    const float* D1w = (const float*)d_in[11];
    const float* D1b = (const float*)d_in[12];
    const float* D2w = (const float*)d_in[13];
    const float* D2b = (const float*)d_in[14];
    const float* n2g = (const float*)d_in[15];
    const float* n2b = (const float*)d_in[16];
    float* out = (float*)d_out;
    float* dh  = (float*)d_ws;

    const size_t DH_BYTES = (size_t)NNODES * HDIM * sizeof(float);   // 10,240,000
    const size_t EW_BYTES = 65536 * 2, D1_BYTES = 65536 * 2, D2_BYTES = 65536 * 2;
    const bool ws_big = ws_size >= DH_BYTES + EW_BYTES + D1_BYTES + D2_BYTES;

    hipMemsetAsync(dh, 0, DH_BYTES, stream);

    if (ws_big) {
        ushort_t* WswE = (ushort_t*)((char*)d_ws + DH_BYTES);
        ushort_t* D1sw = (ushort_t*)((char*)d_ws + DH_BYTES + EW_BYTES);
        ushort_t* D2sw = (ushort_t*)((char*)d_ws + DH_BYTES + EW_BYTES + D1_BYTES);
        prep_edge_weights<<<256, 256, 0, stream>>>(W1w, W2w, W3w, WswE);
        prep_node_weights<<<512, 256, 0, stream>>>(D1w, D2w, D1sw, D2sw);
        edge_mlp_mfma<<<NEDGES / 128, 256, 0, stream>>>(hE, eidx, WswE, W1b, W2b, W3b, dh);
        node_mfma<<<NNODES / 32, 256, 0, stream>>>(hV, dh, n1g, n1b, D1sw, D1b, D2sw, D2b, n2g, n2b, out);
    } else {
        // edge weights in d_out tail (node kernel rewrites all of d_out afterwards)
        ushort_t* WswE = (ushort_t*)((char*)d_out + (size_t)out_size * 4 - EW_BYTES);
        prep_edge_weights<<<256, 256, 0, stream>>>(W1w, W2w, W3w, WswE);
        edge_mlp_mfma<<<NEDGES / 128, 256, 0, stream>>>(hE, eidx, WswE, W1b, W2b, W3b, dh);
        node_update_f32<<<NNODES / NT, 256, 0, stream>>>(hV, dh, n1g, n1b, D1w, D1b, D2w, D2b, n2g, n2b, out);
    }
}